// Round 1
// baseline (781.916 us; speedup 1.0000x reference)
//
#include <hip/hip_runtime.h>
#include <math.h>

#define IN_DIM_C 128
#define OUT_DIM_C 64
#define T_STEPS 8

__device__ __forceinline__ float4 f4zero() { return make_float4(0.f, 0.f, 0.f, 0.f); }

// ---------------- degree: indegree via atomics ----------------
__global__ __launch_bounds__(256) void k_deg(const int* __restrict__ dst,
                                             int* __restrict__ deg, int E) {
    int e = blockIdx.x * 256 + threadIdx.x;
    if (e < E) atomicAdd(&deg[dst[e]], 1);
}

// ---------------- GEMM: h = x @ W  (fp32 vector ALU) ----------------
// block = 256 threads: 16 nodes x 16 dim-groups (4 dims each, float4)
__global__ __launch_bounds__(256) void k_gemm(const float* __restrict__ x,
                                              const float* __restrict__ W,
                                              float* __restrict__ h,
                                              int n, int n_groups) {
    __shared__ __align__(16) float Ws[IN_DIM_C * OUT_DIM_C];   // 32 KB, [k][d]
    __shared__ __align__(16) float xs[16 * 136];               // 16 rows, padded stride 136

    // stage W once (coalesced float4)
    for (int i = threadIdx.x; i < IN_DIM_C * OUT_DIM_C / 4; i += 256)
        ((float4*)Ws)[i] = ((const float4*)W)[i];

    const int ln = threadIdx.x >> 4;   // local node 0..15
    const int dg = threadIdx.x & 15;   // dim group 0..15 -> dims 4*dg..4*dg+3
    const float4* Ws4 = (const float4*)Ws;

    for (int g = blockIdx.x; g < n_groups; g += gridDim.x) {
        int node_base = g * 16;
        __syncthreads();
        // stage 16 x-rows: 512 float4s
        for (int f = threadIdx.x; f < 512; f += 256) {
            int row = f >> 5, c4 = f & 31;
            int node = node_base + row;
            float4 v = f4zero();
            if (node < n) v = *(const float4*)&x[(long)node * IN_DIM_C + c4 * 4];
            *(float4*)&xs[row * 136 + c4 * 4] = v;
        }
        __syncthreads();

        int node = node_base + ln;
        float4 acc = f4zero();
        #pragma unroll
        for (int k = 0; k < IN_DIM_C; k += 4) {
            float4 xv = *(const float4*)&xs[ln * 136 + k];
            float4 w0 = Ws4[(k + 0) * 16 + dg];
            float4 w1 = Ws4[(k + 1) * 16 + dg];
            float4 w2 = Ws4[(k + 2) * 16 + dg];
            float4 w3 = Ws4[(k + 3) * 16 + dg];
            acc.x = fmaf(xv.x, w0.x, acc.x); acc.y = fmaf(xv.x, w0.y, acc.y);
            acc.z = fmaf(xv.x, w0.z, acc.z); acc.w = fmaf(xv.x, w0.w, acc.w);
            acc.x = fmaf(xv.y, w1.x, acc.x); acc.y = fmaf(xv.y, w1.y, acc.y);
            acc.z = fmaf(xv.y, w1.z, acc.z); acc.w = fmaf(xv.y, w1.w, acc.w);
            acc.x = fmaf(xv.z, w2.x, acc.x); acc.y = fmaf(xv.z, w2.y, acc.y);
            acc.z = fmaf(xv.z, w2.z, acc.z); acc.w = fmaf(xv.z, w2.w, acc.w);
            acc.x = fmaf(xv.w, w3.x, acc.x); acc.y = fmaf(xv.w, w3.y, acc.y);
            acc.z = fmaf(xv.w, w3.z, acc.z); acc.w = fmaf(xv.w, w3.w, acc.w);
        }
        if (node < n)
            *(float4*)&h[(long)node * OUT_DIM_C + dg * 4] = acc;
    }
}

// ---------------- init: dinv + self-loop term + bias ----------------
__global__ __launch_bounds__(256) void k_init(const int* __restrict__ deg,
                                              const float* __restrict__ h,
                                              const float* __restrict__ b,
                                              float* __restrict__ agg,
                                              float* __restrict__ dinv, int n) {
    int gid = blockIdx.x * 256 + threadIdx.x;
    int node = gid >> 4, dg = gid & 15;
    if (node >= n) return;
    float d = (float)(deg[node] + 1);           // + self loop
    float di = 1.0f / sqrtf(d);
    if (dg == 0) dinv[node] = di;
    float s = di * di;                           // self-loop norm = 1/deg
    float4 hv = *(const float4*)&h[(long)node * OUT_DIM_C + dg * 4];
    float4 bv = ((const float4*)b)[dg];
    float4 o = make_float4(fmaf(s, hv.x, bv.x), fmaf(s, hv.y, bv.y),
                           fmaf(s, hv.z, bv.z), fmaf(s, hv.w, bv.w));
    *(float4*)&agg[(long)node * OUT_DIM_C + dg * 4] = o;
}

// ---------------- edge scatter: one wave per edge, lane = dim ----------------
__global__ __launch_bounds__(256) void k_scatter(const int* __restrict__ src,
                                                 const int* __restrict__ dst,
                                                 const float* __restrict__ dinv,
                                                 const float* __restrict__ h,
                                                 float* agg, int E) {
    int gid = blockIdx.x * 256 + threadIdx.x;
    int e = gid >> 6;
    int lane = threadIdx.x & 63;
    if (e >= E) return;
    int s = src[e], d = dst[e];
    float norm = dinv[s] * dinv[d];
    float v = norm * h[(long)s * OUT_DIM_C + lane];
    atomicAdd(&agg[(long)d * OUT_DIM_C + lane], v);
}

// ---------------- spiking recurrence: 16 lanes per node, float4/lane ----------------
__global__ __launch_bounds__(256) void k_spike(const float* agg,
                                               float* o_seq, float* z_seq, int n) {
    int gid = blockIdx.x * 256 + threadIdx.x;
    int node = gid >> 4;
    int sub = threadIdx.x & 15;
    if (node >= n) return;
    const float s0 = (sub == 0) ? -1.0f : 1.0f;   // Lorentz sign on dim 0
    int lane0 = (threadIdx.x & 63) & ~15;         // group leader lane in wave

    float4 g = *(const float4*)&agg[(long)node * OUT_DIM_C + sub * 4];
    float4 z = f4zero();
    if (sub == 0) z.x = 1.0f;                     // origin

    for (int t = 0; t < T_STEPS; ++t) {
        // lz = <z, g>_L
        float p = s0 * z.x * g.x + z.y * g.y + z.z * g.z + z.w * g.w;
        p += __shfl_xor(p, 1, 64);
        p += __shfl_xor(p, 2, 64);
        p += __shfl_xor(p, 4, 64);
        p += __shfl_xor(p, 8, 64);
        // u = g + lz*z
        float4 u = make_float4(fmaf(p, z.x, g.x), fmaf(p, z.y, g.y),
                               fmaf(p, z.z, g.z), fmaf(p, z.w, g.w));
        // uu = <u,u>_L
        float q = s0 * u.x * u.x + u.y * u.y + u.z * u.z + u.w * u.w;
        q += __shfl_xor(q, 1, 64);
        q += __shfl_xor(q, 2, 64);
        q += __shfl_xor(q, 4, 64);
        q += __shfl_xor(q, 8, 64);
        float un = sqrtf(fmaxf(q, 1e-7f));
        float c = coshf(un);
        float sh = sinhf(un) / un;
        float4 zn = make_float4(fmaf(c, z.x, sh * u.x), fmaf(c, z.y, sh * u.y),
                                fmaf(c, z.z, sh * u.z), fmaf(c, z.w, sh * u.w));
        float z0 = __shfl(zn.x, lane0, 64);
        float v = acoshf(fmaxf(z0, 1.0f + 1e-7f));
        bool spike = (v >= 1.0f);
        if (spike) { zn = f4zero(); if (sub == 0) zn.x = 1.0f; }
        *(float4*)&z_seq[(long)t * n * OUT_DIM_C + (long)node * OUT_DIM_C + sub * 4] = zn;
        if (sub == 0) o_seq[(long)t * n + node] = spike ? 1.0f : 0.0f;
        z = zn;
    }
}

extern "C" void kernel_launch(void* const* d_in, const int* in_sizes, int n_in,
                              void* d_out, int out_size, void* d_ws, size_t ws_size,
                              hipStream_t stream) {
    const float* x  = (const float*)d_in[0];
    const int*   ei = (const int*)d_in[1];
    const float* W  = (const float*)d_in[2];
    const float* b  = (const float*)d_in[3];
    const int N = in_sizes[0] / IN_DIM_C;   // 100000
    const int E = in_sizes[1] / 2;          // 1600000

    float* out   = (float*)d_out;
    float* o_seq = out;                              // [T, N]
    float* z_seq = out + (long)T_STEPS * N;          // [T, N, 64]

    // scratch aliased into z_seq (each region fully read before being overwritten):
    float* agg  = z_seq;                             // aliases z_seq[0]  (N*64)
    float* h    = z_seq + (long)N * OUT_DIM_C;       // aliases z_seq[1]  (N*64)
    int*   deg  = (int*)(z_seq + 2L * N * OUT_DIM_C);// aliases z_seq[2] start (N ints)
    float* dinv = z_seq + 2L * N * OUT_DIM_C + N;    // next N floats

    const int* src = ei;
    const int* dst = ei + E;

    hipMemsetAsync(deg, 0, (size_t)N * sizeof(int), stream);
    k_deg<<<(E + 255) / 256, 256, 0, stream>>>(dst, deg, E);

    int n_groups = (N + 15) / 16;
    k_gemm<<<1024, 256, 0, stream>>>(x, W, h, N, n_groups);
    k_init<<<(N * 16 + 255) / 256, 256, 0, stream>>>(deg, h, b, agg, dinv, N);

    long scatter_threads = (long)E * 64;
    k_scatter<<<(int)((scatter_threads + 255) / 256), 256, 0, stream>>>(src, dst, dinv, h, agg, E);

    k_spike<<<(N + 15) / 16, 256, 0, stream>>>(agg, o_seq, z_seq, N);
}

// Round 2
// 638.085 us; speedup vs baseline: 1.2254x; 1.2254x over previous
//
#include <hip/hip_runtime.h>
#include <math.h>

#define IN_DIM_C 128
#define OUT_DIM_C 64
#define T_STEPS 8

__device__ __forceinline__ float4 f4zero() { return make_float4(0.f, 0.f, 0.f, 0.f); }

// ---------------- degree: indegree via atomics (400 KB target, L2-resident) ----------------
__global__ __launch_bounds__(256) void k_deg(const int* __restrict__ dst,
                                             int* __restrict__ deg, int E) {
    int e = blockIdx.x * 256 + threadIdx.x;
    if (e < E) atomicAdd(&deg[dst[e]], 1);
}

// ---------------- GEMM: h = x @ W  (fp32 vector ALU) ----------------
__global__ __launch_bounds__(256) void k_gemm(const float* __restrict__ x,
                                              const float* __restrict__ W,
                                              float* __restrict__ h,
                                              int n, int n_groups) {
    __shared__ __align__(16) float Ws[IN_DIM_C * OUT_DIM_C];   // 32 KB, [k][d]
    __shared__ __align__(16) float xs[16 * 136];               // 16 rows, padded stride 136

    for (int i = threadIdx.x; i < IN_DIM_C * OUT_DIM_C / 4; i += 256)
        ((float4*)Ws)[i] = ((const float4*)W)[i];

    const int ln = threadIdx.x >> 4;   // local node 0..15
    const int dg = threadIdx.x & 15;   // dim group 0..15 -> dims 4*dg..4*dg+3
    const float4* Ws4 = (const float4*)Ws;

    for (int g = blockIdx.x; g < n_groups; g += gridDim.x) {
        int node_base = g * 16;
        __syncthreads();
        for (int f = threadIdx.x; f < 512; f += 256) {
            int row = f >> 5, c4 = f & 31;
            int node = node_base + row;
            float4 v = f4zero();
            if (node < n) v = *(const float4*)&x[(long)node * IN_DIM_C + c4 * 4];
            *(float4*)&xs[row * 136 + c4 * 4] = v;
        }
        __syncthreads();

        int node = node_base + ln;
        float4 acc = f4zero();
        #pragma unroll
        for (int k = 0; k < IN_DIM_C; k += 4) {
            float4 xv = *(const float4*)&xs[ln * 136 + k];
            float4 w0 = Ws4[(k + 0) * 16 + dg];
            float4 w1 = Ws4[(k + 1) * 16 + dg];
            float4 w2 = Ws4[(k + 2) * 16 + dg];
            float4 w3 = Ws4[(k + 3) * 16 + dg];
            acc.x = fmaf(xv.x, w0.x, acc.x); acc.y = fmaf(xv.x, w0.y, acc.y);
            acc.z = fmaf(xv.x, w0.z, acc.z); acc.w = fmaf(xv.x, w0.w, acc.w);
            acc.x = fmaf(xv.y, w1.x, acc.x); acc.y = fmaf(xv.y, w1.y, acc.y);
            acc.z = fmaf(xv.y, w1.z, acc.z); acc.w = fmaf(xv.y, w1.w, acc.w);
            acc.x = fmaf(xv.z, w2.x, acc.x); acc.y = fmaf(xv.z, w2.y, acc.y);
            acc.z = fmaf(xv.z, w2.z, acc.z); acc.w = fmaf(xv.z, w2.w, acc.w);
            acc.x = fmaf(xv.w, w3.x, acc.x); acc.y = fmaf(xv.w, w3.y, acc.y);
            acc.z = fmaf(xv.w, w3.z, acc.z); acc.w = fmaf(xv.w, w3.w, acc.w);
        }
        if (node < n)
            *(float4*)&h[(long)node * OUT_DIM_C + dg * 4] = acc;
    }
}

// ---------------- scan: exclusive prefix-sum of deg -> offsets, cursor; also dinv ---------
// Single block, 1024 threads, wave-shuffle scan (4 barriers per 1024-chunk).
__global__ __launch_bounds__(1024) void k_scan(const int* __restrict__ deg,
                                               int* __restrict__ offsets,
                                               int* __restrict__ cursor,
                                               float* __restrict__ dinv, int n) {
    __shared__ int wsum[16];
    __shared__ int woff[16];
    __shared__ int s_carry;
    const int tid = threadIdx.x;
    const int lane = tid & 63;
    const int wv = tid >> 6;
    if (tid == 0) s_carry = 0;
    __syncthreads();
    for (int base = 0; base < n; base += 1024) {
        int i = base + tid;
        int v = (i < n) ? deg[i] : 0;
        int x = v;
        #pragma unroll
        for (int off = 1; off < 64; off <<= 1) {
            int t = __shfl_up(x, off, 64);
            if (lane >= off) x += t;
        }
        if (lane == 63) wsum[wv] = x;
        __syncthreads();
        if (wv == 0) {
            int s = (lane < 16) ? wsum[lane] : 0;
            #pragma unroll
            for (int off = 1; off < 16; off <<= 1) {
                int t = __shfl_up(s, off, 64);
                if (lane >= off) s += t;
            }
            if (lane < 16) woff[lane] = s - wsum[lane];   // exclusive wave offsets
        }
        __syncthreads();
        int carry = s_carry;
        if (i < n) {
            int o = carry + woff[wv] + (x - v);
            offsets[i] = o;
            cursor[i] = o;
            dinv[i] = rsqrtf((float)(v + 1));
        }
        __syncthreads();
        if (tid == 0) s_carry = carry + woff[15] + wsum[15];
        __syncthreads();
    }
    if (tid == 0) offsets[n] = s_carry;
}

// ---------------- bin fill: CSR column build (int atomics on 400 KB cursor) ---------------
__global__ __launch_bounds__(256) void k_fill(const int* __restrict__ src,
                                              const int* __restrict__ dst,
                                              int* __restrict__ cursor,
                                              int* __restrict__ bucket, int E) {
    int e = blockIdx.x * 256 + threadIdx.x;
    if (e >= E) return;
    int d = dst[e];
    int p = atomicAdd(&cursor[d], 1);
    bucket[p] = src[e];
}

// ---------------- pull aggregation: one wave per dst node, lane = dim ---------------------
__global__ __launch_bounds__(256) void k_pull(const int* __restrict__ offsets,
                                              const int* __restrict__ bucket,
                                              const float* __restrict__ dinv,
                                              const float* __restrict__ h,
                                              const float* __restrict__ b,
                                              float* __restrict__ agg, int n) {
    int node = (blockIdx.x * 256 + threadIdx.x) >> 6;
    int lane = threadIdx.x & 63;
    if (node >= n) return;
    int o0 = offsets[node], o1 = offsets[node + 1];
    float dd = dinv[node];
    // self loop (norm = dinv^2) + bias
    float acc = fmaf(dd * dd, h[(long)node * OUT_DIM_C + lane], b[lane]);
    int i = o0;
    for (; i + 4 <= o1; i += 4) {
        int s0 = bucket[i], s1 = bucket[i + 1], s2 = bucket[i + 2], s3 = bucket[i + 3];
        float n0 = dinv[s0] * dd, n1 = dinv[s1] * dd, n2 = dinv[s2] * dd, n3 = dinv[s3] * dd;
        acc = fmaf(n0, h[(long)s0 * OUT_DIM_C + lane], acc);
        acc = fmaf(n1, h[(long)s1 * OUT_DIM_C + lane], acc);
        acc = fmaf(n2, h[(long)s2 * OUT_DIM_C + lane], acc);
        acc = fmaf(n3, h[(long)s3 * OUT_DIM_C + lane], acc);
    }
    for (; i < o1; ++i) {
        int s = bucket[i];
        acc = fmaf(dinv[s] * dd, h[(long)s * OUT_DIM_C + lane], acc);
    }
    agg[(long)node * OUT_DIM_C + lane] = acc;
}

// ---------------- spiking recurrence: 16 lanes/node; cached origin-step fast path ---------
__global__ __launch_bounds__(256) void k_spike(const float* agg,
                                               float* o_seq, float* z_seq, int n) {
    int gid = blockIdx.x * 256 + threadIdx.x;
    int node = gid >> 4;
    int sub = threadIdx.x & 15;
    if (node >= n) return;
    const float s0 = (sub == 0) ? -1.0f : 1.0f;   // Lorentz sign on dim 0
    int lane0 = (threadIdx.x & 63) & ~15;

    float4 g = *(const float4*)&agg[(long)node * OUT_DIM_C + sub * 4];
    float4 origin = f4zero();
    if (sub == 0) origin.x = 1.0f;

    // one manifold step: z -> (zn pre-reset, spike)
    auto step = [&](float4 z, float4& zn, bool& sp) {
        float p = s0 * z.x * g.x + z.y * g.y + z.z * g.z + z.w * g.w;
        p += __shfl_xor(p, 1, 64);
        p += __shfl_xor(p, 2, 64);
        p += __shfl_xor(p, 4, 64);
        p += __shfl_xor(p, 8, 64);
        float4 u = make_float4(fmaf(p, z.x, g.x), fmaf(p, z.y, g.y),
                               fmaf(p, z.z, g.z), fmaf(p, z.w, g.w));
        float q = s0 * u.x * u.x + u.y * u.y + u.z * u.z + u.w * u.w;
        q += __shfl_xor(q, 1, 64);
        q += __shfl_xor(q, 2, 64);
        q += __shfl_xor(q, 4, 64);
        q += __shfl_xor(q, 8, 64);
        float un = sqrtf(fmaxf(q, 1e-7f));
        float c = coshf(un);
        float sh = sinhf(un) / un;
        zn = make_float4(fmaf(c, z.x, sh * u.x), fmaf(c, z.y, sh * u.y),
                         fmaf(c, z.z, sh * u.z), fmaf(c, z.w, sh * u.w));
        float z0 = __shfl(zn.x, lane0, 64);
        float v = acoshf(fmaxf(z0, 1.0f + 1e-7f));
        sp = (v >= 1.0f);
    };

    // cache the step-from-origin result (reused every time state resets)
    float4 z1; bool sp0;
    step(origin, z1, sp0);
    float4 r0 = sp0 ? origin : z1;   // post-reset state after an origin step

    float4 z = origin;
    bool at0 = true;                 // state == origin (group-uniform)
    for (int t = 0; t < T_STEPS; ++t) {
        float4 zn; bool sp;
        if (at0) { sp = sp0; zn = r0; }
        else {
            step(z, zn, sp);
            if (sp) zn = origin;
        }
        *(float4*)&z_seq[(long)t * n * OUT_DIM_C + (long)node * OUT_DIM_C + sub * 4] = zn;
        if (sub == 0) o_seq[(long)t * n + node] = sp ? 1.0f : 0.0f;
        z = zn;
        at0 = sp;
    }
}

extern "C" void kernel_launch(void* const* d_in, const int* in_sizes, int n_in,
                              void* d_out, int out_size, void* d_ws, size_t ws_size,
                              hipStream_t stream) {
    const float* x  = (const float*)d_in[0];
    const int*   ei = (const int*)d_in[1];
    const float* W  = (const float*)d_in[2];
    const float* b  = (const float*)d_in[3];
    const int N = in_sizes[0] / IN_DIM_C;   // 100000
    const int E = in_sizes[1] / 2;          // 1600000

    float* out   = (float*)d_out;
    float* o_seq = out;                              // [T, N]
    float* z_seq = out + (long)T_STEPS * N;          // [T, N, 64]

    // scratch aliased into z_seq slabs (each fully consumed before k_spike overwrites):
    float* agg   = z_seq;                            // slab 0 (read by k_spike first)
    float* h     = z_seq + 1L * N * OUT_DIM_C;       // slab 1
    int*   deg   = (int*)(z_seq + 2L * N * OUT_DIM_C);          // slab 2: N ints
    int*   offsets = deg + N;                                    // N+1 ints
    int*   cursor  = offsets + N + 1;                            // N ints
    float* dinv    = (float*)(cursor + N);                       // N floats
    int*   bucket  = (int*)(z_seq + 3L * N * OUT_DIM_C);        // slab 3: E ints (6.4 MB)

    const int* srcp = ei;
    const int* dstp = ei + E;

    hipMemsetAsync(deg, 0, (size_t)N * sizeof(int), stream);
    k_deg<<<(E + 255) / 256, 256, 0, stream>>>(dstp, deg, E);

    int n_groups = (N + 15) / 16;
    k_gemm<<<1024, 256, 0, stream>>>(x, W, h, N, n_groups);

    k_scan<<<1, 1024, 0, stream>>>(deg, offsets, cursor, dinv, N);
    k_fill<<<(E + 255) / 256, 256, 0, stream>>>(srcp, dstp, cursor, bucket, E);
    k_pull<<<(N * 64 + 255) / 256, 256, 0, stream>>>(offsets, bucket, dinv, h, b, agg, N);

    k_spike<<<(N + 15) / 16, 256, 0, stream>>>(agg, o_seq, z_seq, N);
}